// Round 1
// baseline (690.838 us; speedup 1.0000x reference)
//
#include <hip/hip_runtime.h>
#include <math.h>

#define HD 1024
#define VD 50257
#define SD 2048

// ws layout (floats):
//   [0      .. 1024)  u2        (atomic-accumulated, needs zero)
//   [1024   .. 2048)  context   (atomic-accumulated, needs zero)
//   [2048   .. 4096)  scores
//   [4096   .. 7168)  gA  = W_ih[:, :H] @ emb + b_ih
//   [7168   .. 10240) gh  = W_hh @ h + b_hh
//   [10240  .. 12288) y   = [h_new, context]
//   [12288  .. 12416) lse partials (64 pairs)

__device__ __forceinline__ float wred(float x) {
#pragma unroll
    for (int o = 32; o; o >>= 1) x += __shfl_down(x, o, 64);
    return x;  // valid in lane 0
}

// K1: u2 = attn_W[:,H:]^T @ other ; gh = W_hh@h + b_hh ; gA = W_ih[:, :H]@emb + b_ih
__global__ __launch_bounds__(256) void k_prep(
        const float* __restrict__ attn_W, const float* __restrict__ other,
        const float* __restrict__ W_hh, const float* __restrict__ h,
        const float* __restrict__ b_hh,
        const float* __restrict__ W_ih, const float* __restrict__ b_ih,
        const float* __restrict__ embedding, const int* __restrict__ word,
        float* __restrict__ ws) {
    float* u2 = ws;
    float* gA = ws + 4096;
    float* gh = ws + 7168;
    const int b = blockIdx.x, t = threadIdx.x;
    if (b < 64) {
        // u2[k] = sum_j other[j] * attn_W[j*2048 + 1024 + k]
        const int ktile = b & 3, jc = b >> 2;
        const int k = ktile * 256 + t;
        const float* Wcol = attn_W + 1024 + k;
        const int j0 = jc * 64;
        float acc = 0.f;
#pragma unroll 4
        for (int j = 0; j < 64; ++j)
            acc += other[j0 + j] * Wcol[(size_t)(j0 + j) * 2048];
        atomicAdd(&u2[k], acc);
    } else if (b < 64 + 768) {
        const int row = (b - 64) * 4 + (t >> 6);
        const int lane = t & 63;
        const float4* p = (const float4*)(W_hh + (size_t)row * 1024);
        const float4* q = (const float4*)h;
        float acc = 0.f;
#pragma unroll
        for (int i = lane; i < 256; i += 64) {
            float4 a = p[i], c = q[i];
            acc += a.x * c.x + a.y * c.y + a.z * c.z + a.w * c.w;
        }
        acc = wred(acc);
        if (lane == 0) gh[row] = acc + b_hh[row];
    } else {
        const int row = (b - 832) * 4 + (t >> 6);
        const int lane = t & 63;
        const float* emb = embedding + (size_t)word[0] * 1024;
        const float4* p = (const float4*)(W_ih + (size_t)row * 2048);
        const float4* q = (const float4*)emb;
        float acc = 0.f;
#pragma unroll
        for (int i = lane; i < 256; i += 64) {
            float4 a = p[i], c = q[i];
            acc += a.x * c.x + a.y * c.y + a.z * c.z + a.w * c.w;
        }
        acc = wred(acc);
        if (lane == 0) gA[row] = acc + b_ih[row];
    }
}

// K2: scores[s] = enc[s] . u2
__global__ __launch_bounds__(256) void k_scores(
        const float* __restrict__ enc, const float* __restrict__ ws,
        float* __restrict__ scores) {
    const int row = blockIdx.x * 4 + (threadIdx.x >> 6);
    const int lane = threadIdx.x & 63;
    const float4* p = (const float4*)(enc + (size_t)row * 1024);
    const float4* q = (const float4*)ws;  // u2
    float acc = 0.f;
#pragma unroll
    for (int i = lane; i < 256; i += 64) {
        float4 a = p[i], c = q[i];
        acc += a.x * c.x + a.y * c.y + a.z * c.z + a.w * c.w;
    }
    acc = wred(acc);
    if (lane == 0) scores[row] = acc;
}

// K3: attn = softmax(scores) -> d_out[V+H .. V+H+S)
__global__ __launch_bounds__(256) void k_softmax(
        const float* __restrict__ scores, float* __restrict__ dout) {
    __shared__ float sm[SD];
    __shared__ float wr[8];
    __shared__ float bc;
    const int t = threadIdx.x, lane = t & 63, wave = t >> 6;
    float lm = -INFINITY;
    for (int i = t; i < SD; i += 256) {
        float x = scores[i];
        sm[i] = x;
        lm = fmaxf(lm, x);
    }
#pragma unroll
    for (int o = 32; o; o >>= 1) lm = fmaxf(lm, __shfl_down(lm, o, 64));
    if (lane == 0) wr[wave] = lm;
    __syncthreads();
    if (t == 0) bc = fmaxf(fmaxf(wr[0], wr[1]), fmaxf(wr[2], wr[3]));
    __syncthreads();
    const float M = bc;
    float ls = 0.f;
    for (int i = t; i < SD; i += 256) ls += __expf(sm[i] - M);
#pragma unroll
    for (int o = 32; o; o >>= 1) ls += __shfl_down(ls, o, 64);
    if (lane == 0) wr[4 + wave] = ls;
    __syncthreads();
    if (t == 0) bc = wr[4] + wr[5] + wr[6] + wr[7];
    __syncthreads();
    const float inv = 1.f / bc;
    for (int i = t; i < SD; i += 256) dout[VD + HD + i] = __expf(sm[i] - M) * inv;
}

// K4: context[j] = sum_s attn[s]*enc[s,j]  (atomic partial sums)
__global__ __launch_bounds__(256) void k_context(
        const float* __restrict__ enc, const float* __restrict__ dout,
        float* __restrict__ context) {
    const int b = blockIdx.x;
    const int ct = b & 3, rc = b >> 2;  // 4 col tiles x 16 row chunks
    const int j = ct * 256 + threadIdx.x;
    const float* attn = dout + VD + HD;
    const int r0 = rc * 128;
    float acc = 0.f;
    for (int r = 0; r < 128; ++r)
        acc += attn[r0 + r] * enc[(size_t)(r0 + r) * 1024 + j];
    atomicAdd(&context[j], acc);
}

// K5: finish GRU: gx2 = W_ih[:,H:]@context ; gates ; h_new -> d_out[V..V+H), y
__global__ __launch_bounds__(256) void k_gru(
        const float* __restrict__ W_ih, const float* __restrict__ h,
        float* __restrict__ ws, float* __restrict__ dout) {
    float* context = ws + 1024;
    float* gA = ws + 4096;
    float* gh = ws + 7168;
    float* y = ws + 10240;
    const int i = blockIdx.x * 4 + (threadIdx.x >> 6);
    const int lane = threadIdx.x & 63;
    const float4* q = (const float4*)context;
    float d[3];
#pragma unroll
    for (int g = 0; g < 3; ++g) {
        const float4* p = (const float4*)(W_ih + (size_t)(g * 1024 + i) * 2048 + 1024);
        float a = 0.f;
#pragma unroll
        for (int k = lane; k < 256; k += 64) {
            float4 x = p[k], c = q[k];
            a += x.x * c.x + x.y * c.y + x.z * c.z + x.w * c.w;
        }
        d[g] = wred(a);
    }
    if (lane == 0) {
        const float r = 1.f / (1.f + __expf(-(gA[i] + d[0] + gh[i])));
        const float z = 1.f / (1.f + __expf(-(gA[1024 + i] + d[1] + gh[1024 + i])));
        const float n = tanhf(gA[2048 + i] + d[2] + r * gh[2048 + i]);
        const float hn = (1.f - z) * n + z * h[i];
        dout[VD + i] = hn;
        y[i] = hn;
        y[1024 + i] = context[i];
    }
}

// K6: logits[v] = out_W[v] . y + out_b[v]  (the 412 MB streaming GEMV)
__global__ __launch_bounds__(256) void k_logits(
        const float* __restrict__ out_W, const float* __restrict__ out_b,
        const float* __restrict__ ws, float* __restrict__ dout) {
    __shared__ float4 sy[512];
    const float4* y4 = (const float4*)(ws + 10240);
    const int t = threadIdx.x;
    sy[t] = y4[t];
    sy[t + 256] = y4[t + 256];
    __syncthreads();
    const int row = blockIdx.x * 4 + (t >> 6);
    if (row >= VD) return;
    const int lane = t & 63;
    const float4* p = (const float4*)(out_W + (size_t)row * 2048);
    float acc = 0.f;
#pragma unroll
    for (int i = lane; i < 512; i += 64) {
        float4 a = p[i];
        float4 b = sy[i];
        acc += a.x * b.x + a.y * b.y + a.z * b.z + a.w * b.w;
    }
    acc = wred(acc);
    if (lane == 0) dout[row] = acc + out_b[row];
}

// K7: per-block online (max, sumexp) over logits
__global__ __launch_bounds__(256) void k_lse1(
        const float* __restrict__ dout, float* __restrict__ part) {
    __shared__ float wm[4], wsum[4];
    const int t = threadIdx.x, b = blockIdx.x;
    const int lane = t & 63, wave = t >> 6;
    float m = -INFINITY, s = 0.f;
    for (int v = b * 256 + t; v < VD; v += 64 * 256) {
        float x = dout[v];
        float M = fmaxf(m, x);
        s = s * __expf(m - M) + __expf(x - M);
        m = M;
    }
#pragma unroll
    for (int o = 32; o; o >>= 1) {
        float m2 = __shfl_down(m, o, 64), s2 = __shfl_down(s, o, 64);
        float M = fmaxf(m, m2);
        s = s * __expf(m - M) + s2 * __expf(m2 - M);
        m = M;
    }
    if (lane == 0) { wm[wave] = m; wsum[wave] = s; }
    __syncthreads();
    if (t == 0) {
        float M = wm[0], Ss = wsum[0];
#pragma unroll
        for (int w = 1; w < 4; ++w) {
            float M2 = fmaxf(M, wm[w]);
            Ss = Ss * __expf(M - M2) + wsum[w] * __expf(wm[w] - M2);
            M = M2;
        }
        part[2 * b] = M;
        part[2 * b + 1] = Ss;
    }
}

// K8: combine partials (redundantly per thread, cheap) then log_probs = logits - lse
__global__ __launch_bounds__(256) void k_finish(
        float* __restrict__ dout, const float* __restrict__ part) {
    float m = part[0], s = part[1];
#pragma unroll 8
    for (int i = 1; i < 64; ++i) {
        float m2 = part[2 * i], s2 = part[2 * i + 1];
        float M = fmaxf(m, m2);
        s = s * __expf(m - M) + s2 * __expf(m2 - M);
        m = M;
    }
    const float lse = m + logf(s);
    for (int v = blockIdx.x * 256 + threadIdx.x; v < VD; v += gridDim.x * 256)
        dout[v] -= lse;
}

extern "C" void kernel_launch(void* const* d_in, const int* in_sizes, int n_in,
                              void* d_out, int out_size, void* d_ws, size_t ws_size,
                              hipStream_t stream) {
    const int* word = (const int*)d_in[0];
    const float* h = (const float*)d_in[1];
    const float* enc = (const float*)d_in[2];
    const float* embedding = (const float*)d_in[3];
    const float* attn_W = (const float*)d_in[4];
    // d_in[5] = attn_b: unused — softmax is shift-invariant, the attn_b term is
    // constant across s (scores = enc@u2 + const), so it cancels exactly.
    const float* other = (const float*)d_in[6];
    const float* W_ih = (const float*)d_in[7];
    const float* W_hh = (const float*)d_in[8];
    const float* b_ih = (const float*)d_in[9];
    const float* b_hh = (const float*)d_in[10];
    const float* out_W = (const float*)d_in[11];
    const float* out_b = (const float*)d_in[12];
    float* out = (float*)d_out;
    float* ws = (float*)d_ws;

    // zero the atomic-accumulated regions (u2, context)
    hipMemsetAsync(ws, 0, 2048 * sizeof(float), stream);

    k_prep<<<1600, 256, 0, stream>>>(attn_W, other, W_hh, h, b_hh, W_ih, b_ih,
                                     embedding, word, ws);
    k_scores<<<512, 256, 0, stream>>>(enc, ws, ws + 2048);
    k_softmax<<<1, 256, 0, stream>>>(ws + 2048, out);
    k_context<<<64, 256, 0, stream>>>(enc, out, ws + 1024);
    k_gru<<<256, 256, 0, stream>>>(W_ih, h, ws, out);
    k_logits<<<(VD + 3) / 4, 256, 0, stream>>>(out_W, out_b, ws, out);
    k_lse1<<<64, 256, 0, stream>>>(out, ws + 12288);
    k_finish<<<128, 256, 0, stream>>>(out, ws + 12288);
}

// Round 3
// 681.081 us; speedup vs baseline: 1.0143x; 1.0143x over previous
//
#include <hip/hip_runtime.h>
#include <math.h>

#define HD 1024
#define VD 50257
#define SD 2048
#define NVB 12565          // ceil(VD/4) row-groups for vocab GEMV kernels

// ws float layout:
//   [0     .. 1024)  u2       (atomic, memset to 0)
//   [1024  .. 2048)  context  (atomic, memset to 0)
//   [2048  .. 4096)  scores
//   [4096  .. 5120)  hvec (h_new)
//   [8192  .. 8192+VD)   psum = out_W[:,H:] @ context
//   [61440 .. 61440+2*NVB) lse partials (m,s) per k_fin block

__device__ __forceinline__ float wred(float x) {
#pragma unroll
    for (int o = 32; o; o >>= 1) x += __shfl_down(x, o, 64);
    return x;  // valid in lane 0
}

// K1: u2 = attn_W[:,H:]^T @ other  (attn_b dropped: constant shift, softmax-invariant)
__global__ __launch_bounds__(256) void k_u2(
        const float* __restrict__ attn_W, const float* __restrict__ other,
        float* __restrict__ ws) {
    const int b = blockIdx.x, t = threadIdx.x;
    const int kt = b & 3, jc = b >> 2;           // 4 k-tiles x 64 j-chunks
    const int k = kt * 256 + t;
    const float* Wcol = attn_W + HD + k;
    const int j0 = jc * 16;
    float acc = 0.f;
#pragma unroll
    for (int j = 0; j < 16; ++j)
        acc += other[j0 + j] * Wcol[(size_t)(j0 + j) * (2 * HD)];
    atomicAdd(&ws[k], acc);
}

// K2: scores[s] = enc[s] . u2
__global__ __launch_bounds__(256) void k_scores(
        const float* __restrict__ enc, const float* __restrict__ ws,
        float* __restrict__ scores) {
    const int row = blockIdx.x * 4 + (threadIdx.x >> 6);
    const int lane = threadIdx.x & 63;
    const float4* p = (const float4*)(enc + (size_t)row * HD);
    const float4* q = (const float4*)ws;  // u2
    float acc = 0.f;
#pragma unroll
    for (int i = lane; i < 256; i += 64) {
        float4 a = p[i], c = q[i];
        acc += a.x * c.x + a.y * c.y + a.z * c.z + a.w * c.w;
    }
    acc = wred(acc);
    if (lane == 0) scores[row] = acc;
}

// K3: redundant per-block softmax (8KB) + context partials; block 0 writes attn out.
__global__ __launch_bounds__(256) void k_ctx(
        const float* __restrict__ enc, const float* __restrict__ scores,
        float* __restrict__ context, float* __restrict__ dout) {
    __shared__ float sm[SD];
    __shared__ float wr[8];
    __shared__ float bc;
    const int t = threadIdx.x, lane = t & 63, wave = t >> 6;
    float lm = -INFINITY;
    for (int i = t; i < SD; i += 256) {
        float x = scores[i];
        sm[i] = x;
        lm = fmaxf(lm, x);
    }
#pragma unroll
    for (int o = 32; o; o >>= 1) lm = fmaxf(lm, __shfl_down(lm, o, 64));
    if (lane == 0) wr[wave] = lm;
    __syncthreads();
    if (t == 0) bc = fmaxf(fmaxf(wr[0], wr[1]), fmaxf(wr[2], wr[3]));
    __syncthreads();
    const float M = bc;
    float ls = 0.f;
    for (int i = t; i < SD; i += 256) ls += __expf(sm[i] - M);
#pragma unroll
    for (int o = 32; o; o >>= 1) ls += __shfl_down(ls, o, 64);
    if (lane == 0) wr[4 + wave] = ls;
    __syncthreads();
    if (t == 0) bc = wr[4] + wr[5] + wr[6] + wr[7];
    __syncthreads();
    const float inv = 1.f / bc;
    for (int i = t; i < SD; i += 256) sm[i] = __expf(sm[i] - M) * inv;
    __syncthreads();
    if (blockIdx.x == 0)
        for (int i = t; i < SD; i += 256) dout[VD + HD + i] = sm[i];
    // context partial: 32 row-chunks x 4 col-tiles
    const int rc = blockIdx.x >> 2, ct = blockIdx.x & 3;
    const int j = ct * 256 + t;
    const int r0 = rc * 64;
    float acc = 0.f;
#pragma unroll 4
    for (int r = 0; r < 64; ++r)
        acc += sm[r0 + r] * enc[(size_t)(r0 + r) * HD + j];
    atomicAdd(&context[j], acc);
}

// K4: blocks [0,256): full GRU (gA,gh,gx2 computed locally) -> h_new.
//     blocks [256,..): psum[row] = out_W[row, H:2H] . context
__global__ __launch_bounds__(256) void k_big(
        const float* __restrict__ out_W, const float* __restrict__ W_ih,
        const float* __restrict__ W_hh, const float* __restrict__ b_ih,
        const float* __restrict__ b_hh, const float* __restrict__ embedding,
        const int* __restrict__ word, const float* __restrict__ h,
        float* __restrict__ ws, float* __restrict__ dout) {
    __shared__ float4 sv[256];
    const int t = threadIdx.x, lane = t & 63, wave = t >> 6;
    const float* ctx = ws + 1024;
    if (blockIdx.x < 256) {
        const int i = blockIdx.x * 4 + wave;
        const float4* e4 = (const float4*)(embedding + (size_t)word[0] * HD);
        const float4* h4 = (const float4*)h;
        const float4* c4 = (const float4*)ctx;
        float ga[3], gx[3], gh[3];
#pragma unroll
        for (int g = 0; g < 3; ++g) {
            const int row = g * HD + i;
            const float4* pa = (const float4*)(W_ih + (size_t)row * 2 * HD);
            const float4* px = pa + 256;
            const float4* ph = (const float4*)(W_hh + (size_t)row * HD);
            float a = 0.f, x = 0.f, hh = 0.f;
#pragma unroll
            for (int k = lane; k < 256; k += 64) {
                float4 w1 = pa[k], w2 = px[k], w3 = ph[k];
                float4 v1 = e4[k], v2 = c4[k], v3 = h4[k];
                a += w1.x * v1.x + w1.y * v1.y + w1.z * v1.z + w1.w * v1.w;
                x += w2.x * v2.x + w2.y * v2.y + w2.z * v2.z + w2.w * v2.w;
                hh += w3.x * v3.x + w3.y * v3.y + w3.z * v3.z + w3.w * v3.w;
            }
            ga[g] = wred(a); gx[g] = wred(x); gh[g] = wred(hh);
        }
        if (lane == 0) {
            const float r = 1.f / (1.f + __expf(-(ga[0] + gx[0] + b_ih[i] + gh[0] + b_hh[i])));
            const float z = 1.f / (1.f + __expf(-(ga[1] + gx[1] + b_ih[HD + i] + gh[1] + b_hh[HD + i])));
            const float n = tanhf(ga[2] + gx[2] + b_ih[2 * HD + i] + r * (gh[2] + b_hh[2 * HD + i]));
            const float hn = (1.f - z) * n + z * h[i];
            dout[VD + i] = hn;
            ws[4096 + i] = hn;
        }
    } else {
        sv[t] = ((const float4*)ctx)[t];
        __syncthreads();
        const int row = (blockIdx.x - 256) * 4 + wave;
        if (row >= VD) return;
        const float4* p = (const float4*)(out_W + (size_t)row * 2 * HD + HD);
        float acc = 0.f;
#pragma unroll
        for (int i = lane; i < 256; i += 64) {
            float4 a = p[i], c = sv[i];
            acc += a.x * c.x + a.y * c.y + a.z * c.z + a.w * c.w;
        }
        acc = wred(acc);
        if (lane == 0) ws[8192 + row] = acc;
    }
}

// K5: logits[row] = out_W[row, :H] . h_new + psum[row] + out_b[row]; block lse partial.
__global__ __launch_bounds__(256) void k_fin(
        const float* __restrict__ out_W, const float* __restrict__ out_b,
        float* __restrict__ ws, float* __restrict__ dout) {
    __shared__ float4 sh[256];
    __shared__ float lgt[4];
    const int t = threadIdx.x, lane = t & 63, wave = t >> 6;
    sh[t] = ((const float4*)(ws + 4096))[t];
    __syncthreads();
    const int row = blockIdx.x * 4 + wave;
    float logit = -INFINITY;
    if (row < VD) {
        const float4* p = (const float4*)(out_W + (size_t)row * 2 * HD);
        float acc = 0.f;
#pragma unroll
        for (int i = lane; i < 256; i += 64) {
            float4 a = p[i], c = sh[i];
            acc += a.x * c.x + a.y * c.y + a.z * c.z + a.w * c.w;
        }
        acc = wred(acc);
        if (lane == 0) {
            logit = acc + ws[8192 + row] + out_b[row];
            dout[row] = logit;
        }
    }
    if (lane == 0) lgt[wave] = logit;
    __syncthreads();
    if (t == 0) {
        const float m = fmaxf(fmaxf(lgt[0], lgt[1]), fmaxf(lgt[2], lgt[3]));
        float s = 0.f;
#pragma unroll
        for (int w = 0; w < 4; ++w) s += __expf(lgt[w] - m);  // exp(-inf)=0 for pads
        ws[61440 + 2 * blockIdx.x] = m;
        ws[61440 + 2 * blockIdx.x + 1] = s;
    }
}

// K6: each block redundantly reduces the (m,s) partials (bit-identical order),
//     then subtracts lse from its 256 logits.
__global__ __launch_bounds__(256) void k_sub(
        float* __restrict__ dout, const float* __restrict__ ws) {
    __shared__ float wm[4], wsm[4];
    __shared__ float lsef;
    const int t = threadIdx.x, lane = t & 63, wave = t >> 6;
    const float* part = ws + 61440;
    float m = -INFINITY, s = 0.f;
    for (int i = t; i < NVB; i += 256) {
        float m2 = part[2 * i], s2 = part[2 * i + 1];
        float M = fmaxf(m, m2);
        s = s * __expf(m - M) + s2 * __expf(m2 - M);
        m = M;
    }
#pragma unroll
    for (int o = 32; o; o >>= 1) {
        float m2 = __shfl_down(m, o, 64), s2 = __shfl_down(s, o, 64);
        float M = fmaxf(m, m2);
        s = s * __expf(m - M) + s2 * __expf(m2 - M);
        m = M;
    }
    if (lane == 0) { wm[wave] = m; wsm[wave] = s; }
    __syncthreads();
    if (t == 0) {
        float M = wm[0], S = wsm[0];
#pragma unroll
        for (int w = 1; w < 4; ++w) {
            float M2 = fmaxf(M, wm[w]);
            S = S * __expf(M - M2) + wsm[w] * __expf(wm[w] - M2);
            M = M2;
        }
        lsef = M + logf(S);
    }
    __syncthreads();
    const int v = blockIdx.x * 256 + t;
    if (v < VD) dout[v] -= lsef;
}

extern "C" void kernel_launch(void* const* d_in, const int* in_sizes, int n_in,
                              void* d_out, int out_size, void* d_ws, size_t ws_size,
                              hipStream_t stream) {
    const int* word = (const int*)d_in[0];
    const float* h = (const float*)d_in[1];
    const float* enc = (const float*)d_in[2];
    const float* embedding = (const float*)d_in[3];
    const float* attn_W = (const float*)d_in[4];
    // d_in[5] = attn_b unused: scores = enc@u2 + const; softmax shift-invariant.
    const float* other = (const float*)d_in[6];
    const float* W_ih = (const float*)d_in[7];
    const float* W_hh = (const float*)d_in[8];
    const float* b_ih = (const float*)d_in[9];
    const float* b_hh = (const float*)d_in[10];
    const float* out_W = (const float*)d_in[11];
    const float* out_b = (const float*)d_in[12];
    float* out = (float*)d_out;
    float* ws = (float*)d_ws;

    hipMemsetAsync(ws, 0, 2048 * sizeof(float), stream);  // u2 + context
    k_u2<<<256, 256, 0, stream>>>(attn_W, other, ws);
    k_scores<<<512, 256, 0, stream>>>(enc, ws, ws + 2048);
    k_ctx<<<128, 256, 0, stream>>>(enc, ws + 2048, ws + 1024, out);
    k_big<<<256 + NVB, 256, 0, stream>>>(out_W, W_ih, W_hh, b_ih, b_hh,
                                         embedding, word, h, ws, out);
    k_fin<<<NVB, 256, 0, stream>>>(out_W, out_b, ws, out);
    k_sub<<<197, 256, 0, stream>>>(out, ws);
}